// Round 3
// baseline (1191.705 us; speedup 1.0000x reference)
//
#include <hip/hip_runtime.h>
#include <hip/hip_bf16.h>

typedef __attribute__((ext_vector_type(8))) __bf16 bf16x8;
typedef __attribute__((ext_vector_type(4))) float f32x4;

#define SEQ 2048
#define NH 32
#define NKV 8
#define HD 128

__device__ __forceinline__ ushort f2bf(float f) {
  unsigned u = __builtin_bit_cast(unsigned, f);
  unsigned r = (u + 0x7fffu + ((u >> 16) & 1u)) >> 16;  // RNE
  return (ushort)r;
}
__device__ __forceinline__ float bf2f(ushort h) {
  return __builtin_bit_cast(float, ((unsigned)h) << 16);
}
__device__ __forceinline__ void gload16(const void* g, void* l) {
  __builtin_amdgcn_global_load_lds(
      (const __attribute__((address_space(1))) void*)g,
      (__attribute__((address_space(3))) void*)l, 16, 0, 0);
}

// ---------------- f32 -> bf16 convert ----------------
__global__ __launch_bounds__(256) void f2bf_kernel(const float4* __restrict__ in,
                                                   ushort4* __restrict__ out, int n4) {
  int i = blockIdx.x * 256 + threadIdx.x;
  if (i >= n4) return;
  float4 v = in[i];
  ushort4 o;
  o.x = f2bf(v.x); o.y = f2bf(v.y); o.z = f2bf(v.z); o.w = f2bf(v.w);
  out[i] = o;
}

// ---------------- GEMM: C[M][N] = A[M][K] * B[N][K]^T (bf16 in, bf16/f32 out) ----------------
template <int OUTF32>
__global__ __launch_bounds__(256) void gemm_bt_kernel(const ushort* __restrict__ A,
                                                      const ushort* __restrict__ B,
                                                      void* __restrict__ C,
                                                      int M, int N, int K) {
  __shared__ ushort As[2][128 * 32];
  __shared__ ushort Bs[2][128 * 32];
  const int tid = threadIdx.x;
  const int w = tid >> 6, l = tid & 63;
  const int lr = l & 15, lc = l >> 4;
  const int bx = blockIdx.x, by = blockIdx.y;
  const int wr = w >> 1, wc = w & 1;

  f32x4 z = {0.f, 0.f, 0.f, 0.f};
  f32x4 acc[4][4];
#pragma unroll
  for (int i = 0; i < 4; ++i)
#pragma unroll
    for (int j = 0; j < 4; ++j) acc[i][j] = z;

  const ushort* aSrc = A + (size_t)(by * 128 + 32 * w + (l >> 2)) * K + (l & 3) * 8;
  const ushort* bSrc = B + (size_t)(bx * 128 + 32 * w + (l >> 2)) * K + (l & 3) * 8;
  const int ldsOff = (32 * w) * 32;

#pragma unroll
  for (int q = 0; q < 2; ++q) {
    gload16(aSrc + (size_t)q * 16 * K, &As[0][ldsOff + q * 512]);
    gload16(bSrc + (size_t)q * 16 * K, &Bs[0][ldsOff + q * 512]);
  }
  __syncthreads();

  const int nk = K >> 5;
  int cur = 0;
  for (int kt = 0; kt < nk; ++kt) {
    if (kt + 1 < nk) {
      const ushort* a2 = aSrc + (size_t)(kt + 1) * 32;
      const ushort* b2 = bSrc + (size_t)(kt + 1) * 32;
#pragma unroll
      for (int q = 0; q < 2; ++q) {
        gload16(a2 + (size_t)q * 16 * K, &As[cur ^ 1][ldsOff + q * 512]);
        gload16(b2 + (size_t)q * 16 * K, &Bs[cur ^ 1][ldsOff + q * 512]);
      }
    }
    bf16x8 af[4], bfr[4];
#pragma unroll
    for (int i = 0; i < 4; ++i)
      af[i] = *(const bf16x8*)&As[cur][(64 * wr + 16 * i + lr) * 32 + lc * 8];
#pragma unroll
    for (int j = 0; j < 4; ++j)
      bfr[j] = *(const bf16x8*)&Bs[cur][(64 * wc + 16 * j + lr) * 32 + lc * 8];
#pragma unroll
    for (int i = 0; i < 4; ++i)
#pragma unroll
      for (int j = 0; j < 4; ++j)
        acc[i][j] = __builtin_amdgcn_mfma_f32_16x16x32_bf16(af[i], bfr[j], acc[i][j], 0, 0, 0);
    __syncthreads();
    cur ^= 1;
  }

#pragma unroll
  for (int i = 0; i < 4; ++i)
#pragma unroll
    for (int j = 0; j < 4; ++j) {
      int row = by * 128 + 64 * wr + 16 * i + lc * 4;
      int col = bx * 128 + 64 * wc + 16 * j + lr;
#pragma unroll
      for (int r = 0; r < 4; ++r) {
        if (OUTF32)
          ((float*)C)[(size_t)(row + r) * N + col] = acc[i][j][r];
        else
          ((ushort*)C)[(size_t)(row + r) * N + col] = f2bf(acc[i][j][r]);
      }
    }
}

// ---------------- RoPE + relayout to [b][h][s][d] ----------------
__global__ __launch_bounds__(256) void rope_kernel(const ushort* __restrict__ in,
                                                   const float* __restrict__ cosb,
                                                   const float* __restrict__ sinb,
                                                   ushort* __restrict__ out,
                                                   int hshift, float scale) {
  int idx = blockIdx.x * 256 + threadIdx.x;
  int d = idx & 63;
  int nh = 1 << hshift;
  int h = (idx >> 6) & (nh - 1);
  int rowg = idx >> (6 + hshift);  // b*SEQ + s
  int s = rowg & (SEQ - 1);
  int b = rowg >> 11;
  const ushort* p = in + (size_t)rowg * (nh * HD) + h * HD + d;
  float x = bf2f(p[0]), y = bf2f(p[64]);
  float c = cosb[s * HD + d], sn = sinb[s * HD + d];
  ushort* qo = out + (((size_t)(b * nh + h)) * SEQ + s) * HD + d;
  qo[0] = f2bf((x * c - y * sn) * scale);
  qo[64] = f2bf((y * c + x * sn) * scale);
}

// ---------------- V transpose: [b*S][nkv*128] -> [b][kvh][d][s] ----------------
__global__ __launch_bounds__(256) void vtrans_kernel(const ushort* __restrict__ vin,
                                                     ushort* __restrict__ vout) {
  __shared__ ushort t[64][66];
  const int s0 = blockIdx.x * 64;
  const int c0 = blockIdx.y * 64;
  const int b = blockIdx.z;
  const int tx = threadIdx.x & 63;
  const int ty = threadIdx.x >> 6;
#pragma unroll
  for (int rr = 0; rr < 64; rr += 4) {
    int r = rr + ty;
    t[r][tx] = vin[((size_t)(b * SEQ + s0 + r)) * (NKV * HD) + c0 + tx];
  }
  __syncthreads();
#pragma unroll
  for (int rr = 0; rr < 64; rr += 4) {
    int c = rr + ty;
    int cg = c0 + c;
    int kvh = cg >> 7, d = cg & 127;
    vout[(((size_t)(b * NKV + kvh)) * HD + d) * SEQ + s0 + tx] = t[tx][c];
  }
}

// ---------------- Flash attention (causal, GQA) ----------------
// 1024 blocks (XCD-swizzled), 4 waves/block, each wave owns 32 q-rows and runs
// barrier-free over its own causal KV range. K/V fragments read directly from
// global (L2-resident per XCD: 2 (b,kvh) pairs = 2MB < 4MB). Only per-wave P
// staging uses LDS (16KB/block).
__global__ __launch_bounds__(256) void attn_kernel(const ushort* __restrict__ Qh,
                                                   const ushort* __restrict__ Kh,
                                                   const ushort* __restrict__ Vt,
                                                   ushort* __restrict__ Out) {
  __shared__ ushort Pl[4][32 * 64];  // per-wave P staging, swizzled (16KB)

  const int tid = threadIdx.x;
  const int w = tid >> 6, l = tid & 63;
  const int lr = l & 15, lc = l >> 4;

  // XCD-aware decode: XCD x (= n%8) owns (b,kvh) pairs {2x, 2x+1}
  const int n = blockIdx.x;
  const int m = ((n & 7) << 7) + (n >> 3);  // sorted index
  const int pp = m >> 6;                    // b*8 + kvh
  const int rm = m & 63;
  const int h2 = rm >> 4;                   // head within group
  const int qx = rm & 15;
  const int qt = (qx & 1) ? (15 - (qx >> 1)) : (qx >> 1);  // causal balance
  const int b = pp >> 3, kvh = pp & 7;
  const int h = kvh * 4 + h2;
  const int bh = b * 32 + h;
  const int q0 = qt * 128;
  const int wrow0 = q0 + 32 * w;

  const ushort* Qbase = Qh + ((size_t)bh * SEQ + q0) * HD;
  const ushort* Kbase = Kh + ((size_t)(b * NKV + kvh) * SEQ) * HD;
  const ushort* Vbase = Vt + ((size_t)(b * NKV + kvh) * HD) * SEQ;

  // Q fragments in registers (Q pre-scaled by 1/sqrt(128) in rope)
  bf16x8 qf[2][4];
#pragma unroll
  for (int qr = 0; qr < 2; ++qr) {
    const ushort* qrow = Qbase + (size_t)(32 * w + 16 * qr + lr) * HD + lc * 8;
#pragma unroll
    for (int kc = 0; kc < 4; ++kc) qf[qr][kc] = *(const bf16x8*)(qrow + kc * 32);
  }

  f32x4 z = {0.f, 0.f, 0.f, 0.f};
  f32x4 o[2][8];
#pragma unroll
  for (int qr = 0; qr < 2; ++qr)
#pragma unroll
    for (int db = 0; db < 8; ++db) o[qr][db] = z;
  float m_run[2][4], l_run[2][4];
#pragma unroll
  for (int qr = 0; qr < 2; ++qr)
#pragma unroll
    for (int r = 0; r < 4; ++r) { m_run[qr][r] = -1e30f; l_run[qr][r] = 0.f; }

  ushort* pw = (ushort*)&Pl[w][0];
  const int ntw = (wrow0 >> 6) + 1;  // this wave's causal tile count

  for (int t = 0; t < ntw; ++t) {
    const int kv0 = t * 64;

    // S = Q K^T  (K fragments direct from global/L2)
    f32x4 sacc[2][4];
#pragma unroll
    for (int qr = 0; qr < 2; ++qr)
#pragma unroll
      for (int cb = 0; cb < 4; ++cb) sacc[qr][cb] = z;
    __builtin_amdgcn_s_setprio(1);
#pragma unroll
    for (int cb = 0; cb < 4; ++cb) {
      const ushort* krow = Kbase + (size_t)(kv0 + 16 * cb + lr) * HD + lc * 8;
      bf16x8 kf[4];
#pragma unroll
      for (int kc = 0; kc < 4; ++kc) kf[kc] = *(const bf16x8*)(krow + kc * 32);
#pragma unroll
      for (int kc = 0; kc < 4; ++kc) {
        sacc[0][cb] = __builtin_amdgcn_mfma_f32_16x16x32_bf16(qf[0][kc], kf[kc], sacc[0][cb], 0, 0, 0);
        sacc[1][cb] = __builtin_amdgcn_mfma_f32_16x16x32_bf16(qf[1][kc], kf[kc], sacc[1][cb], 0, 0, 0);
      }
    }
    __builtin_amdgcn_s_setprio(0);

    if (t == ntw - 1) {  // diagonal tile: causal mask
#pragma unroll
      for (int qr = 0; qr < 2; ++qr)
#pragma unroll
        for (int cb = 0; cb < 4; ++cb)
#pragma unroll
          for (int r = 0; r < 4; ++r) {
            int col = kv0 + 16 * cb + lr;
            int rowq = wrow0 + 16 * qr + lc * 4 + r;
            if (col > rowq) sacc[qr][cb][r] = -1e30f;
          }
    }

    // online softmax with defer-max (T13): skip O-rescale when max barely grows
    float mnew[2][4];
    bool ok = true;
#pragma unroll
    for (int qr = 0; qr < 2; ++qr)
#pragma unroll
      for (int r = 0; r < 4; ++r) {
        float mx = fmaxf(fmaxf(sacc[qr][0][r], sacc[qr][1][r]),
                         fmaxf(sacc[qr][2][r], sacc[qr][3][r]));
#pragma unroll
        for (int off = 8; off; off >>= 1) mx = fmaxf(mx, __shfl_xor(mx, off));
        mnew[qr][r] = mx;
        ok = ok && (mx <= m_run[qr][r] + 8.0f);
      }
    if (!__all(ok)) {
#pragma unroll
      for (int qr = 0; qr < 2; ++qr)
#pragma unroll
        for (int r = 0; r < 4; ++r) {
          float mn = fmaxf(m_run[qr][r], mnew[qr][r]);
          float sc = __expf(m_run[qr][r] - mn);
          m_run[qr][r] = mn;
          l_run[qr][r] *= sc;
#pragma unroll
          for (int db = 0; db < 8; ++db) o[qr][db][r] *= sc;
        }
    }
#pragma unroll
    for (int qr = 0; qr < 2; ++qr)
#pragma unroll
      for (int r = 0; r < 4; ++r) {
        int prow = 16 * qr + lc * 4 + r;
        float s = 0.f;
#pragma unroll
        for (int cb = 0; cb < 4; ++cb) {
          float e = __expf(sacc[qr][cb][r] - m_run[qr][r]);
          s += e;
          *(ushort*)((char*)pw + prow * 128 +
                     (((16 * cb + lr) * 2) ^ ((prow & 7) << 4))) = f2bf(e);
        }
#pragma unroll
        for (int off = 8; off; off >>= 1) s += __shfl_xor(s, off);
        l_run[qr][r] += s;
      }

    // O += P V  (V^T fragments direct from global/L2)
#pragma unroll
    for (int c = 0; c < 2; ++c) {
      bf16x8 pa[2];
#pragma unroll
      for (int qr = 0; qr < 2; ++qr)
        pa[qr] = *(const bf16x8*)((const char*)pw + (16 * qr + lr) * 128 +
                                  ((64 * c + lc * 16) ^ ((lr & 7) << 4)));
      bf16x8 vf[8];
#pragma unroll
      for (int db = 0; db < 8; ++db)
        vf[db] = *(const bf16x8*)(Vbase + (size_t)(16 * db + lr) * SEQ + kv0 + 32 * c + lc * 8);
      __builtin_amdgcn_s_setprio(1);
#pragma unroll
      for (int db = 0; db < 8; ++db) {
        o[0][db] = __builtin_amdgcn_mfma_f32_16x16x32_bf16(pa[0], vf[db], o[0][db], 0, 0, 0);
        o[1][db] = __builtin_amdgcn_mfma_f32_16x16x32_bf16(pa[1], vf[db], o[1][db], 0, 0, 0);
      }
      __builtin_amdgcn_s_setprio(0);
    }
  }

  // normalize and write: Out[b*S + row][h*128 + d]  (bf16)
#pragma unroll
  for (int qr = 0; qr < 2; ++qr)
#pragma unroll
    for (int r = 0; r < 4; ++r) {
      float inv = 1.0f / l_run[qr][r];
      int rowq = q0 + 32 * w + 16 * qr + lc * 4 + r;
      size_t base = ((size_t)b * SEQ + rowq) * (NH * HD) + h * HD;
#pragma unroll
      for (int db = 0; db < 8; ++db) Out[base + 16 * db + lr] = f2bf(o[qr][db][r] * inv);
    }
}

extern "C" void kernel_launch(void* const* d_in, const int* in_sizes, int n_in,
                              void* d_out, int out_size, void* d_ws, size_t ws_size,
                              hipStream_t stream) {
  const float* hs = (const float*)d_in[0];
  // d_in[1] = attention_mask: exactly causal, applied analytically in attn_kernel
  const float* cosb = (const float*)d_in[2];
  const float* sinb = (const float*)d_in[3];
  const float* wq = (const float*)d_in[4];
  const float* wk = (const float*)d_in[5];
  const float* wv = (const float*)d_in[6];
  const float* wo = (const float*)d_in[7];

  char* ws = (char*)d_ws;
  ushort* hs_bf = (ushort*)(ws);               // 33.5MB [4096][4096]
  ushort* wq_bf = (ushort*)(ws + 33554432);    // 33.5MB
  ushort* wk_bf = (ushort*)(ws + 67108864);    // 8.4MB
  ushort* wv_bf = (ushort*)(ws + 75497472);    // 8.4MB
  ushort* wo_bf = (ushort*)(ws + 83886080);    // 33.5MB
  ushort* q_lin = (ushort*)(ws + 117440512);   // 33.5MB [4096][4096]
  ushort* k_lin = (ushort*)(ws + 150994944);   // 8.4MB  [4096][1024]
  ushort* v_lin = (ushort*)(ws + 159383552);   // 8.4MB  (ends at 160MB)
  // aliases into regions dead after the projections:
  ushort* Qh = hs_bf;                          // [B][32][S][128]
  ushort* Kh = wq_bf;                          // [B][8][S][128]
  ushort* Vt = (ushort*)(ws + 41943040);       // [B][8][128][S]
  ushort* attn_out = q_lin;                    // [4096][4096]

  f2bf_kernel<<<16384, 256, 0, stream>>>((const float4*)hs, (ushort4*)hs_bf, 4194304);
  f2bf_kernel<<<16384, 256, 0, stream>>>((const float4*)wq, (ushort4*)wq_bf, 4194304);
  f2bf_kernel<<<4096, 256, 0, stream>>>((const float4*)wk, (ushort4*)wk_bf, 1048576);
  f2bf_kernel<<<4096, 256, 0, stream>>>((const float4*)wv, (ushort4*)wv_bf, 1048576);
  f2bf_kernel<<<16384, 256, 0, stream>>>((const float4*)wo, (ushort4*)wo_bf, 4194304);

  gemm_bt_kernel<0><<<dim3(32, 32), 256, 0, stream>>>(hs_bf, wq_bf, q_lin, 4096, 4096, 4096);
  gemm_bt_kernel<0><<<dim3(8, 32), 256, 0, stream>>>(hs_bf, wk_bf, k_lin, 4096, 1024, 4096);
  gemm_bt_kernel<0><<<dim3(8, 32), 256, 0, stream>>>(hs_bf, wv_bf, v_lin, 4096, 1024, 4096);

  rope_kernel<<<32768, 256, 0, stream>>>(q_lin, cosb, sinb, Qh, 5, 0.08838834764831845f);
  rope_kernel<<<8192, 256, 0, stream>>>(k_lin, cosb, sinb, Kh, 3, 1.0f);
  vtrans_kernel<<<dim3(32, 16, 2), 256, 0, stream>>>(v_lin, Vt);

  attn_kernel<<<1024, 256, 0, stream>>>(Qh, Kh, Vt, attn_out);

  gemm_bt_kernel<1><<<dim3(32, 32), 256, 0, stream>>>(attn_out, wo_bf, d_out, 4096, 4096, 4096);
}

// Round 4
// 827.668 us; speedup vs baseline: 1.4398x; 1.4398x over previous
//
#include <hip/hip_runtime.h>
#include <hip/hip_bf16.h>

typedef __attribute__((ext_vector_type(8))) __bf16 bf16x8;
typedef __attribute__((ext_vector_type(4))) float f32x4;
typedef __attribute__((ext_vector_type(16))) float f32x16;
typedef __attribute__((ext_vector_type(4))) unsigned int u32x4;

#define SEQ 2048
#define NH 32
#define NKV 8
#define HD 128

__device__ __forceinline__ ushort f2bf(float f) {
  unsigned u = __builtin_bit_cast(unsigned, f);
  unsigned r = (u + 0x7fffu + ((u >> 16) & 1u)) >> 16;  // RNE
  return (ushort)r;
}
__device__ __forceinline__ float bf2f(ushort h) {
  return __builtin_bit_cast(float, ((unsigned)h) << 16);
}
__device__ __forceinline__ unsigned cvt_pk_bf16(float lo, float hi) {
  unsigned r;
  asm("v_cvt_pk_bf16_f32 %0, %1, %2" : "=v"(r) : "v"(lo), "v"(hi));
  return r;
}
__device__ __forceinline__ void gload16(const void* g, void* l) {
  __builtin_amdgcn_global_load_lds(
      (const __attribute__((address_space(1))) void*)g,
      (__attribute__((address_space(3))) void*)l, 16, 0, 0);
}

// ---------------- f32 -> bf16 convert ----------------
__global__ __launch_bounds__(256) void f2bf_kernel(const float4* __restrict__ in,
                                                   ushort4* __restrict__ out, int n4) {
  int i = blockIdx.x * 256 + threadIdx.x;
  if (i >= n4) return;
  float4 v = in[i];
  ushort4 o;
  o.x = f2bf(v.x); o.y = f2bf(v.y); o.z = f2bf(v.z); o.w = f2bf(v.w);
  out[i] = o;
}

// ---------------- GEMM: C[M][N] = A[M][K] * B[N][K]^T (bf16 in, bf16/f32 out) ----------------
template <int OUTF32>
__global__ __launch_bounds__(256) void gemm_bt_kernel(const ushort* __restrict__ A,
                                                      const ushort* __restrict__ B,
                                                      void* __restrict__ C,
                                                      int M, int N, int K) {
  __shared__ ushort As[2][128 * 32];
  __shared__ ushort Bs[2][128 * 32];
  const int tid = threadIdx.x;
  const int w = tid >> 6, l = tid & 63;
  const int lr = l & 15, lc = l >> 4;
  const int bx = blockIdx.x, by = blockIdx.y;
  const int wr = w >> 1, wc = w & 1;

  f32x4 z = {0.f, 0.f, 0.f, 0.f};
  f32x4 acc[4][4];
#pragma unroll
  for (int i = 0; i < 4; ++i)
#pragma unroll
    for (int j = 0; j < 4; ++j) acc[i][j] = z;

  const ushort* aSrc = A + (size_t)(by * 128 + 32 * w + (l >> 2)) * K + (l & 3) * 8;
  const ushort* bSrc = B + (size_t)(bx * 128 + 32 * w + (l >> 2)) * K + (l & 3) * 8;
  const int ldsOff = (32 * w) * 32;

#pragma unroll
  for (int q = 0; q < 2; ++q) {
    gload16(aSrc + (size_t)q * 16 * K, &As[0][ldsOff + q * 512]);
    gload16(bSrc + (size_t)q * 16 * K, &Bs[0][ldsOff + q * 512]);
  }
  __syncthreads();

  const int nk = K >> 5;
  int cur = 0;
  for (int kt = 0; kt < nk; ++kt) {
    if (kt + 1 < nk) {
      const ushort* a2 = aSrc + (size_t)(kt + 1) * 32;
      const ushort* b2 = bSrc + (size_t)(kt + 1) * 32;
#pragma unroll
      for (int q = 0; q < 2; ++q) {
        gload16(a2 + (size_t)q * 16 * K, &As[cur ^ 1][ldsOff + q * 512]);
        gload16(b2 + (size_t)q * 16 * K, &Bs[cur ^ 1][ldsOff + q * 512]);
      }
    }
    bf16x8 af[4], bfr[4];
#pragma unroll
    for (int i = 0; i < 4; ++i)
      af[i] = *(const bf16x8*)&As[cur][(64 * wr + 16 * i + lr) * 32 + lc * 8];
#pragma unroll
    for (int j = 0; j < 4; ++j)
      bfr[j] = *(const bf16x8*)&Bs[cur][(64 * wc + 16 * j + lr) * 32 + lc * 8];
#pragma unroll
    for (int i = 0; i < 4; ++i)
#pragma unroll
      for (int j = 0; j < 4; ++j)
        acc[i][j] = __builtin_amdgcn_mfma_f32_16x16x32_bf16(af[i], bfr[j], acc[i][j], 0, 0, 0);
    __syncthreads();
    cur ^= 1;
  }

#pragma unroll
  for (int i = 0; i < 4; ++i)
#pragma unroll
    for (int j = 0; j < 4; ++j) {
      int row = by * 128 + 64 * wr + 16 * i + lc * 4;
      int col = bx * 128 + 64 * wc + 16 * j + lr;
#pragma unroll
      for (int r = 0; r < 4; ++r) {
        if (OUTF32)
          ((float*)C)[(size_t)(row + r) * N + col] = acc[i][j][r];
        else
          ((ushort*)C)[(size_t)(row + r) * N + col] = f2bf(acc[i][j][r]);
      }
    }
}

// ---------------- RoPE + relayout to [b][h][s][d] ----------------
__global__ __launch_bounds__(256) void rope_kernel(const ushort* __restrict__ in,
                                                   const float* __restrict__ cosb,
                                                   const float* __restrict__ sinb,
                                                   ushort* __restrict__ out,
                                                   int hshift, float scale) {
  int idx = blockIdx.x * 256 + threadIdx.x;
  int d = idx & 63;
  int nh = 1 << hshift;
  int h = (idx >> 6) & (nh - 1);
  int rowg = idx >> (6 + hshift);  // b*SEQ + s
  int s = rowg & (SEQ - 1);
  int b = rowg >> 11;
  const ushort* p = in + (size_t)rowg * (nh * HD) + h * HD + d;
  float x = bf2f(p[0]), y = bf2f(p[64]);
  float c = cosb[s * HD + d], sn = sinb[s * HD + d];
  ushort* qo = out + (((size_t)(b * nh + h)) * SEQ + s) * HD + d;
  qo[0] = f2bf((x * c - y * sn) * scale);
  qo[64] = f2bf((y * c + x * sn) * scale);
}

// ---------------- V transpose: [b*S][nkv*128] -> [b][kvh][d][s] ----------------
__global__ __launch_bounds__(256) void vtrans_kernel(const ushort* __restrict__ vin,
                                                     ushort* __restrict__ vout) {
  __shared__ ushort t[64][66];
  const int s0 = blockIdx.x * 64;
  const int c0 = blockIdx.y * 64;
  const int b = blockIdx.z;
  const int tx = threadIdx.x & 63;
  const int ty = threadIdx.x >> 6;
#pragma unroll
  for (int rr = 0; rr < 64; rr += 4) {
    int r = rr + ty;
    t[r][tx] = vin[((size_t)(b * SEQ + s0 + r)) * (NKV * HD) + c0 + tx];
  }
  __syncthreads();
#pragma unroll
  for (int rr = 0; rr < 64; rr += 4) {
    int c = rr + ty;
    int cg = c0 + c;
    int kvh = cg >> 7, d = cg & 127;
    vout[(((size_t)(b * NKV + kvh)) * HD + d) * SEQ + s0 + tx] = t[tx][c];
  }
}

// ---------------- Flash attention (causal, GQA), swapped-operand 32x32 ----------------
// 1024 blocks (XCD-swizzled), 4 waves, 32 q-rows/wave. S^T = mfma(K,Q): each lane
// owns ONE q column (lane&31), 32 kv values in regs -> softmax is lane-local
// (1 shfl per reduce). P stays in registers (cvt_pk + one shfl_xor(32) per
// k-step feeds PV's B operand). K staged in LDS (dbuf, swizzled); V^T direct
// from global (L2-resident), O^T accumulated 32x32.
__global__ __launch_bounds__(256, 2) void attn_kernel(const ushort* __restrict__ Qh,
                                                      const ushort* __restrict__ Kh,
                                                      const ushort* __restrict__ Vt,
                                                      ushort* __restrict__ Out) {
  __shared__ ushort Kl[2][64 * 128];  // 2 x 16KB, XOR-swizzled rows

  const int tid = threadIdx.x;
  const int w = tid >> 6, l = tid & 63;
  const int lq = l & 31;   // this lane's q column
  const int hl = l >> 5;   // lane half

  // XCD-aware decode: XCD (n%8) owns (b,kvh) pairs {2x,2x+1}
  const int n = blockIdx.x;
  const int m = ((n & 7) << 7) + (n >> 3);
  const int pp = m >> 6;  // bb*8 + kvh
  const int rm = m & 63;
  const int h2 = rm >> 4;
  const int qx = rm & 15;
  const int qt = (qx & 1) ? (15 - (qx >> 1)) : (qx >> 1);  // causal balance
  const int bb = pp >> 3, kvh = pp & 7;
  const int hh = kvh * 4 + h2;
  const int bh = bb * 32 + hh;
  const int q0 = qt * 128;
  const int wrow0 = q0 + 32 * w;
  const int qrow = wrow0 + lq;

  const ushort* Kbase = Kh + ((size_t)(bb * NKV + kvh) * SEQ) * HD;
  const ushort* Vbase = Vt + ((size_t)(bb * NKV + kvh) * HD) * SEQ;

  // Q fragments (B-operand: col=q=lane&31, k = 8*hl + j within each 16-step)
  bf16x8 qf[8];
  {
    const ushort* qrp = Qh + ((size_t)bh * SEQ + qrow) * HD + 8 * hl;
#pragma unroll
    for (int s8 = 0; s8 < 8; ++s8) qf[s8] = *(const bf16x8*)(qrp + 16 * s8);
  }

  f32x16 o[4];
#pragma unroll
  for (int db = 0; db < 4; ++db)
#pragma unroll
    for (int i = 0; i < 16; ++i) o[db][i] = 0.f;
  float m_run = -1e30f, l_run = 0.f;

  const int ntw = 2 * qt + (w >> 1) + 1;  // this wave's causal tile count
  const int ntb = 2 * qt + 2;             // block tile count

  auto stageK = [&](int buf, int t) {
    const int kv0 = t * 64;
#pragma unroll
    for (int q = 0; q < 4; ++q) {
      int chunk = 4 * w + q;
      int row = chunk * 4 + (l >> 4);
      int cs = ((l & 15) ^ (row & 7)) * 8;
      gload16(Kbase + ((size_t)(kv0 + row)) * HD + cs, &Kl[buf][chunk * 512]);
    }
  };

  stageK(0, 0);
  __syncthreads();

  int cur = 0;
  for (int t = 0; t < ntb; ++t) {
    const int kv0 = t * 64;
    if (t + 1 < ntb) stageK(cur ^ 1, t + 1);

    if (t < ntw) {
      // S^T = K * Q : C[row=kv][col=q]
      f32x16 sacc[2];
#pragma unroll
      for (int b = 0; b < 2; ++b)
#pragma unroll
        for (int i = 0; i < 16; ++i) sacc[b][i] = 0.f;

      const int swz = lq & 7;
      __builtin_amdgcn_s_setprio(1);
#pragma unroll
      for (int s8 = 0; s8 < 8; ++s8) {
#pragma unroll
        for (int b = 0; b < 2; ++b) {
          int row = 32 * b + lq;
          bf16x8 kf = *(const bf16x8*)((const char*)&Kl[cur][0] + row * 256 +
                                       (((2 * s8 + hl) ^ swz) << 4));
          sacc[b] = __builtin_amdgcn_mfma_f32_32x32x16_bf16(kf, qf[s8], sacc[b], 0, 0, 0);
        }
      }
      __builtin_amdgcn_s_setprio(0);

      if (t == ntw - 1) {  // diagonal tile: causal mask (kv > q)
#pragma unroll
        for (int b = 0; b < 2; ++b)
#pragma unroll
          for (int r = 0; r < 16; ++r) {
            int kv = kv0 + 32 * b + (r & 3) + 8 * (r >> 2) + 4 * hl;
            if (kv > qrow) sacc[b][r] = -1e30f;
          }
      }

      // lane-local softmax
      float mx = sacc[0][0];
#pragma unroll
      for (int r = 1; r < 16; ++r) mx = fmaxf(mx, sacc[0][r]);
#pragma unroll
      for (int r = 0; r < 16; ++r) mx = fmaxf(mx, sacc[1][r]);
      mx = fmaxf(mx, __shfl_xor(mx, 32));

      if (__any(mx > m_run + 8.0f)) {  // defer-max (T13)
        float mn = fmaxf(m_run, mx);
        float sc = __expf(m_run - mn);
        m_run = mn;
        l_run *= sc;
#pragma unroll
        for (int db = 0; db < 4; ++db) o[db] *= sc;
      }

      float sum = 0.f;
#pragma unroll
      for (int b = 0; b < 2; ++b)
#pragma unroll
        for (int r = 0; r < 16; ++r) {
          float e = __expf(sacc[b][r] - m_run);
          sacc[b][r] = e;
          sum += e;
        }
      sum += __shfl_xor(sum, 32);
      l_run += sum;

      // pack P to bf16 pairs: pw[b][i] = (kv_even, kv_odd)
      unsigned pw[2][8];
#pragma unroll
      for (int b = 0; b < 2; ++b)
#pragma unroll
        for (int i = 0; i < 8; ++i)
          pw[b][i] = cvt_pk_bf16(sacc[b][2 * i], sacc[b][2 * i + 1]);

      // O^T += V^T * P : per k-step s (kv 16s..16s+15)
#pragma unroll
      for (int s = 0; s < 4; ++s) {
        const int b = s >> 1, bs = 4 * (s & 1);
        unsigned wA = pw[b][bs], wB = pw[b][bs + 1], wC = pw[b][bs + 2], wD = pw[b][bs + 3];
        unsigned s1 = hl ? wA : wC, s2 = hl ? wB : wD;
        unsigned rx1 = (unsigned)__shfl_xor((int)s1, 32);
        unsigned rx2 = (unsigned)__shfl_xor((int)s2, 32);
        u32x4 fw = {hl ? rx1 : wA, hl ? rx2 : wB, hl ? wC : rx1, hl ? wD : rx2};
        bf16x8 pfrag = __builtin_bit_cast(bf16x8, fw);
        const ushort* vp = Vbase + (size_t)lq * SEQ + kv0 + 16 * s + 8 * hl;
        bf16x8 vf[4];
#pragma unroll
        for (int db = 0; db < 4; ++db) vf[db] = *(const bf16x8*)(vp + (size_t)(32 * db) * SEQ);
        __builtin_amdgcn_s_setprio(1);
#pragma unroll
        for (int db = 0; db < 4; ++db)
          o[db] = __builtin_amdgcn_mfma_f32_32x32x16_bf16(vf[db], pfrag, o[db], 0, 0, 0);
        __builtin_amdgcn_s_setprio(0);
      }
    }
    __syncthreads();
    cur ^= 1;
  }

  // write O^T: lane's column q = qrow; rows d = 32db + (r&3)+8*(r>>2)+4*hl
  const float inv = 1.0f / l_run;
  ushort* outp = Out + ((size_t)bb * SEQ + qrow) * (NH * HD) + hh * HD;
#pragma unroll
  for (int db = 0; db < 4; ++db)
#pragma unroll
    for (int i = 0; i < 8; ++i) {
      unsigned wrd = cvt_pk_bf16(o[db][2 * i] * inv, o[db][2 * i + 1] * inv);
      int d = 32 * db + 2 * (i & 1) + 8 * (i >> 1) + 4 * hl;
      *(unsigned*)(outp + d) = wrd;
    }
}

extern "C" void kernel_launch(void* const* d_in, const int* in_sizes, int n_in,
                              void* d_out, int out_size, void* d_ws, size_t ws_size,
                              hipStream_t stream) {
  const float* hs = (const float*)d_in[0];
  // d_in[1] = attention_mask: exactly causal, applied analytically in attn_kernel
  const float* cosb = (const float*)d_in[2];
  const float* sinb = (const float*)d_in[3];
  const float* wq = (const float*)d_in[4];
  const float* wk = (const float*)d_in[5];
  const float* wv = (const float*)d_in[6];
  const float* wo = (const float*)d_in[7];

  char* ws = (char*)d_ws;
  ushort* hs_bf = (ushort*)(ws);               // 33.5MB [4096][4096]
  ushort* wq_bf = (ushort*)(ws + 33554432);    // 33.5MB
  ushort* wk_bf = (ushort*)(ws + 67108864);    // 8.4MB
  ushort* wv_bf = (ushort*)(ws + 75497472);    // 8.4MB
  ushort* wo_bf = (ushort*)(ws + 83886080);    // 33.5MB
  ushort* q_lin = (ushort*)(ws + 117440512);   // 33.5MB [4096][4096]
  ushort* k_lin = (ushort*)(ws + 150994944);   // 8.4MB  [4096][1024]
  ushort* v_lin = (ushort*)(ws + 159383552);   // 8.4MB  (ends at 160MB)
  // aliases into regions dead after the projections:
  ushort* Qh = hs_bf;                          // [B][32][S][128]
  ushort* Kh = wq_bf;                          // [B][8][S][128]
  ushort* Vt = (ushort*)(ws + 41943040);       // [B][8][128][S]
  ushort* attn_out = q_lin;                    // [4096][4096]

  f2bf_kernel<<<16384, 256, 0, stream>>>((const float4*)hs, (ushort4*)hs_bf, 4194304);
  f2bf_kernel<<<16384, 256, 0, stream>>>((const float4*)wq, (ushort4*)wq_bf, 4194304);
  f2bf_kernel<<<4096, 256, 0, stream>>>((const float4*)wk, (ushort4*)wk_bf, 1048576);
  f2bf_kernel<<<4096, 256, 0, stream>>>((const float4*)wv, (ushort4*)wv_bf, 1048576);
  f2bf_kernel<<<16384, 256, 0, stream>>>((const float4*)wo, (ushort4*)wo_bf, 4194304);

  gemm_bt_kernel<0><<<dim3(32, 32), 256, 0, stream>>>(hs_bf, wq_bf, q_lin, 4096, 4096, 4096);
  gemm_bt_kernel<0><<<dim3(8, 32), 256, 0, stream>>>(hs_bf, wk_bf, k_lin, 4096, 1024, 4096);
  gemm_bt_kernel<0><<<dim3(8, 32), 256, 0, stream>>>(hs_bf, wv_bf, v_lin, 4096, 1024, 4096);

  rope_kernel<<<32768, 256, 0, stream>>>(q_lin, cosb, sinb, Qh, 5, 0.08838834764831845f);
  rope_kernel<<<8192, 256, 0, stream>>>(k_lin, cosb, sinb, Kh, 3, 1.0f);
  vtrans_kernel<<<dim3(32, 16, 2), 256, 0, stream>>>(v_lin, Vt);

  attn_kernel<<<1024, 256, 0, stream>>>(Qh, Kh, Vt, attn_out);

  gemm_bt_kernel<1><<<dim3(32, 32), 256, 0, stream>>>(attn_out, wo_bf, d_out, 4096, 4096, 4096);
}

// Round 5
// 622.270 us; speedup vs baseline: 1.9151x; 1.3301x over previous
//
#include <hip/hip_runtime.h>
#include <hip/hip_bf16.h>

typedef __attribute__((ext_vector_type(8))) __bf16 bf16x8;
typedef __attribute__((ext_vector_type(4))) float f32x4;
typedef __attribute__((ext_vector_type(16))) float f32x16;
typedef __attribute__((ext_vector_type(4))) unsigned int u32x4;

#define SEQ 2048
#define NH 32
#define NKV 8
#define HD 128

__device__ __forceinline__ ushort f2bf(float f) {
  unsigned u = __builtin_bit_cast(unsigned, f);
  unsigned r = (u + 0x7fffu + ((u >> 16) & 1u)) >> 16;  // RNE
  return (ushort)r;
}
__device__ __forceinline__ float bf2f(ushort h) {
  return __builtin_bit_cast(float, ((unsigned)h) << 16);
}
__device__ __forceinline__ unsigned cvt_pk_bf16(float lo, float hi) {
  unsigned r;
  asm("v_cvt_pk_bf16_f32 %0, %1, %2" : "=v"(r) : "v"(lo), "v"(hi));
  return r;
}
__device__ __forceinline__ void gload16(const void* g, void* l) {
  __builtin_amdgcn_global_load_lds(
      (const __attribute__((address_space(1))) void*)g,
      (__attribute__((address_space(3))) void*)l, 16, 0, 0);
}

// ---------------- f32 -> bf16 convert ----------------
__global__ __launch_bounds__(256) void f2bf_kernel(const float4* __restrict__ in,
                                                   ushort4* __restrict__ out, int n4) {
  int i = blockIdx.x * 256 + threadIdx.x;
  if (i >= n4) return;
  float4 v = in[i];
  ushort4 o;
  o.x = f2bf(v.x); o.y = f2bf(v.y); o.z = f2bf(v.z); o.w = f2bf(v.w);
  out[i] = o;
}

// ---------------- 128^2 GEMM (m97 structure): C = A * B^T ----------------
template <int OUTF32>
__global__ __launch_bounds__(256) void gemm_bt_kernel(const ushort* __restrict__ A,
                                                      const ushort* __restrict__ B,
                                                      void* __restrict__ C,
                                                      int M, int N, int K) {
  __shared__ ushort As[2][128 * 32];
  __shared__ ushort Bs[2][128 * 32];
  const int tid = threadIdx.x;
  const int w = tid >> 6, l = tid & 63;
  const int lr = l & 15, lc = l >> 4;
  const int bx = blockIdx.x, by = blockIdx.y;
  const int wr = w >> 1, wc = w & 1;

  f32x4 z = {0.f, 0.f, 0.f, 0.f};
  f32x4 acc[4][4];
#pragma unroll
  for (int i = 0; i < 4; ++i)
#pragma unroll
    for (int j = 0; j < 4; ++j) acc[i][j] = z;

  const ushort* aSrc = A + (size_t)(by * 128 + 32 * w + (l >> 2)) * K + (l & 3) * 8;
  const ushort* bSrc = B + (size_t)(bx * 128 + 32 * w + (l >> 2)) * K + (l & 3) * 8;
  const int ldsOff = (32 * w) * 32;

#pragma unroll
  for (int q = 0; q < 2; ++q) {
    gload16(aSrc + (size_t)q * 16 * K, &As[0][ldsOff + q * 512]);
    gload16(bSrc + (size_t)q * 16 * K, &Bs[0][ldsOff + q * 512]);
  }
  __syncthreads();

  const int nk = K >> 5;
  int cur = 0;
  for (int kt = 0; kt < nk; ++kt) {
    if (kt + 1 < nk) {
      const ushort* a2 = aSrc + (size_t)(kt + 1) * 32;
      const ushort* b2 = bSrc + (size_t)(kt + 1) * 32;
#pragma unroll
      for (int q = 0; q < 2; ++q) {
        gload16(a2 + (size_t)q * 16 * K, &As[cur ^ 1][ldsOff + q * 512]);
        gload16(b2 + (size_t)q * 16 * K, &Bs[cur ^ 1][ldsOff + q * 512]);
      }
    }
    bf16x8 af[4], bfr[4];
#pragma unroll
    for (int i = 0; i < 4; ++i)
      af[i] = *(const bf16x8*)&As[cur][(64 * wr + 16 * i + lr) * 32 + lc * 8];
#pragma unroll
    for (int j = 0; j < 4; ++j)
      bfr[j] = *(const bf16x8*)&Bs[cur][(64 * wc + 16 * j + lr) * 32 + lc * 8];
#pragma unroll
    for (int i = 0; i < 4; ++i)
#pragma unroll
      for (int j = 0; j < 4; ++j)
        acc[i][j] = __builtin_amdgcn_mfma_f32_16x16x32_bf16(af[i], bfr[j], acc[i][j], 0, 0, 0);
    __syncthreads();
    cur ^= 1;
  }

#pragma unroll
  for (int i = 0; i < 4; ++i)
#pragma unroll
    for (int j = 0; j < 4; ++j) {
      int row = by * 128 + 64 * wr + 16 * i + lc * 4;
      int col = bx * 128 + 64 * wc + 16 * j + lr;
#pragma unroll
      for (int r = 0; r < 4; ++r) {
        if (OUTF32)
          ((float*)C)[(size_t)(row + r) * N + col] = acc[i][j][r];
        else
          ((ushort*)C)[(size_t)(row + r) * N + col] = f2bf(acc[i][j][r]);
      }
    }
}

// ---------------- 256^2 8-phase GEMM (m201 template): C = A * B^T ----------------
// 512 thr = 8 waves (2M x 4N), BK=64, 128 KiB LDS dbuf, 4 phases/K-tile of
// 16 MFMA, 1 half-tile stage (2 gload_lds) per phase, counted vmcnt(2) + one
// barrier per K-tile. G4 swizzle (row&7)<<4 on stage-source and ds_read.
template <int OUTF32>
__global__ __launch_bounds__(512, 2) void gemm256_kernel(const ushort* __restrict__ A,
                                                         const ushort* __restrict__ B,
                                                         void* __restrict__ C,
                                                         int M, int N, int K) {
  __shared__ ushort As[2][256 * 64];  // 64 KB
  __shared__ ushort Bs[2][256 * 64];  // 64 KB
  const int tid = threadIdx.x;
  const int w = tid >> 6, l = tid & 63;
  const int lr = l & 15, lc = l >> 4;
  const int wr = w >> 2, wc = w & 3;

  // XCD-chunked swizzle (grid must be multiple of 8; 256 here)
  const int nbx = N >> 8;
  const int cpx = gridDim.x >> 3;
  const int sw = (blockIdx.x & 7) * cpx + (blockIdx.x >> 3);
  const int bx = sw % nbx, by = sw / nbx;

  const ushort* Asrc = A + (size_t)(by * 256) * K;
  const ushort* Bsrc = B + (size_t)(bx * 256) * K;

  f32x4 z = {0.f, 0.f, 0.f, 0.f};
  f32x4 acc[8][4];
#pragma unroll
  for (int m = 0; m < 8; ++m)
#pragma unroll
    for (int n = 0; n < 4; ++n) acc[m][n] = z;

  const int NK = K >> 6;

  // stage s: 0=A rows 0-127, 1=A rows 128-255, 2=B rows 0-127, 3=B rows 128-255
  // (2 gload_lds per wave per stage; lane l writes lds base + l*16)
  auto stage = [&](int kt2, int s) {
    if (kt2 >= NK) return;
    const int mat = s >> 1, half = s & 1;
    const ushort* g = mat ? Bsrc : Asrc;
    char* lb = (char*)(mat ? &Bs[kt2 & 1][0] : &As[kt2 & 1][0]) + half * 16384 + w * 1024;
#pragma unroll
    for (int i = 0; i < 2; ++i) {
      int row = half * 128 + i * 64 + w * 8 + (l >> 3);
      int csw = ((l & 7) * 16) ^ ((row & 7) << 4);  // inverse-swizzled source col
      gload16(g + (size_t)row * K + kt2 * 64 + (csw >> 1), lb + i * 8192);
    }
  };

  // prologue: K-tile 0 fully + K-tile 1's first half-tile
  stage(0, 0); stage(0, 1); stage(0, 2); stage(0, 3);
  stage(1, 0);

  bf16x8 af[4][2], bfr[4][2];
  for (int kt = 0; kt < NK; ++kt) {
    const char* Ab = (const char*)&As[kt & 1][0];
    const char* Bb = (const char*)&Bs[kt & 1][0];
    // boundary: kt's 8 loads are the oldest outstanding; kt+1 s0 (2) may fly on
    if (kt + 1 < NK) asm volatile("s_waitcnt vmcnt(2)" ::: "memory");
    else             asm volatile("s_waitcnt vmcnt(0)" ::: "memory");
    asm volatile("s_barrier" ::: "memory");

    // ---- phase A: quadrant m0-3 x n0-1 ----
#pragma unroll
    for (int m = 0; m < 4; ++m) {
      int row = wr * 128 + m * 16 + lr;
#pragma unroll
      for (int ks = 0; ks < 2; ++ks)
        af[m][ks] = *(const bf16x8*)(Ab + row * 128 + ((ks * 64 + lc * 16) ^ ((row & 7) << 4)));
    }
#pragma unroll
    for (int n = 0; n < 2; ++n) {
      int row = wc * 64 + n * 16 + lr;
#pragma unroll
      for (int ks = 0; ks < 2; ++ks)
        bfr[n][ks] = *(const bf16x8*)(Bb + row * 128 + ((ks * 64 + lc * 16) ^ ((row & 7) << 4)));
    }
    stage(kt + 1, 1);  // A-h1 of next tile (other buffer; its last reads done pre-boundary)
    __builtin_amdgcn_s_setprio(1);
#pragma unroll
    for (int m = 0; m < 4; ++m)
#pragma unroll
      for (int n = 0; n < 2; ++n)
#pragma unroll
        for (int ks = 0; ks < 2; ++ks)
          acc[m][n] = __builtin_amdgcn_mfma_f32_16x16x32_bf16(af[m][ks], bfr[n][ks], acc[m][n], 0, 0, 0);
    __builtin_amdgcn_s_setprio(0);
    asm volatile("s_barrier" ::: "memory");

    // ---- phase B: quadrant m0-3 x n2-3 ----
#pragma unroll
    for (int n = 2; n < 4; ++n) {
      int row = wc * 64 + n * 16 + lr;
#pragma unroll
      for (int ks = 0; ks < 2; ++ks)
        bfr[n][ks] = *(const bf16x8*)(Bb + row * 128 + ((ks * 64 + lc * 16) ^ ((row & 7) << 4)));
    }
    stage(kt + 1, 2);  // B-h0 next tile
    __builtin_amdgcn_s_setprio(1);
#pragma unroll
    for (int m = 0; m < 4; ++m)
#pragma unroll
      for (int n = 2; n < 4; ++n)
#pragma unroll
        for (int ks = 0; ks < 2; ++ks)
          acc[m][n] = __builtin_amdgcn_mfma_f32_16x16x32_bf16(af[m][ks], bfr[n][ks], acc[m][n], 0, 0, 0);
    __builtin_amdgcn_s_setprio(0);
    asm volatile("s_barrier" ::: "memory");

    // ---- phase C: quadrant m4-7 x n0-1 ----
#pragma unroll
    for (int m = 0; m < 4; ++m) {
      int row = wr * 128 + (m + 4) * 16 + lr;
#pragma unroll
      for (int ks = 0; ks < 2; ++ks)
        af[m][ks] = *(const bf16x8*)(Ab + row * 128 + ((ks * 64 + lc * 16) ^ ((row & 7) << 4)));
    }
    stage(kt + 1, 3);  // B-h1 next tile
    __builtin_amdgcn_s_setprio(1);
#pragma unroll
    for (int m = 0; m < 4; ++m)
#pragma unroll
      for (int n = 0; n < 2; ++n)
#pragma unroll
        for (int ks = 0; ks < 2; ++ks)
          acc[m + 4][n] = __builtin_amdgcn_mfma_f32_16x16x32_bf16(af[m][ks], bfr[n][ks], acc[m + 4][n], 0, 0, 0);
    __builtin_amdgcn_s_setprio(0);
    asm volatile("s_barrier" ::: "memory");

    // ---- phase D: quadrant m4-7 x n2-3 (no ds_reads) ----
    // stage kt+2 A-h0 into THIS buffer: rows 0-127 were last ds_read in
    // phases A (0-63) / C (64-127), all complete before phase-C barrier.
    stage(kt + 2, 0);
    __builtin_amdgcn_s_setprio(1);
#pragma unroll
    for (int m = 0; m < 4; ++m)
#pragma unroll
      for (int n = 2; n < 4; ++n)
#pragma unroll
        for (int ks = 0; ks < 2; ++ks)
          acc[m + 4][n] = __builtin_amdgcn_mfma_f32_16x16x32_bf16(af[m][ks], bfr[n][ks], acc[m + 4][n], 0, 0, 0);
    __builtin_amdgcn_s_setprio(0);
    // no barrier here: next iteration's boundary vmcnt+barrier covers phase D
  }

#pragma unroll
  for (int m = 0; m < 8; ++m)
#pragma unroll
    for (int n = 0; n < 4; ++n) {
      int row = by * 256 + wr * 128 + m * 16 + lc * 4;
      int col = bx * 256 + wc * 64 + n * 16 + lr;
#pragma unroll
      for (int r = 0; r < 4; ++r) {
        if (OUTF32)
          ((float*)C)[(size_t)(row + r) * N + col] = acc[m][n][r];
        else
          ((ushort*)C)[(size_t)(row + r) * N + col] = f2bf(acc[m][n][r]);
      }
    }
}

// ---------------- RoPE + relayout to [b][h][s][d] ----------------
__global__ __launch_bounds__(256) void rope_kernel(const ushort* __restrict__ in,
                                                   const float* __restrict__ cosb,
                                                   const float* __restrict__ sinb,
                                                   ushort* __restrict__ out,
                                                   int hshift, float scale) {
  int idx = blockIdx.x * 256 + threadIdx.x;
  int d = idx & 63;
  int nh = 1 << hshift;
  int h = (idx >> 6) & (nh - 1);
  int rowg = idx >> (6 + hshift);  // b*SEQ + s
  int s = rowg & (SEQ - 1);
  int b = rowg >> 11;
  const ushort* p = in + (size_t)rowg * (nh * HD) + h * HD + d;
  float x = bf2f(p[0]), y = bf2f(p[64]);
  float c = cosb[s * HD + d], sn = sinb[s * HD + d];
  ushort* qo = out + (((size_t)(b * nh + h)) * SEQ + s) * HD + d;
  qo[0] = f2bf((x * c - y * sn) * scale);
  qo[64] = f2bf((y * c + x * sn) * scale);
}

// ---------------- V transpose: [b*S][nkv*128] -> [b][kvh][d][s] ----------------
__global__ __launch_bounds__(256) void vtrans_kernel(const ushort* __restrict__ vin,
                                                     ushort* __restrict__ vout) {
  __shared__ ushort t[64][66];
  const int s0 = blockIdx.x * 64;
  const int c0 = blockIdx.y * 64;
  const int b = blockIdx.z;
  const int tx = threadIdx.x & 63;
  const int ty = threadIdx.x >> 6;
#pragma unroll
  for (int rr = 0; rr < 64; rr += 4) {
    int r = rr + ty;
    t[r][tx] = vin[((size_t)(b * SEQ + s0 + r)) * (NKV * HD) + c0 + tx];
  }
  __syncthreads();
#pragma unroll
  for (int rr = 0; rr < 64; rr += 4) {
    int c = rr + ty;
    int cg = c0 + c;
    int kvh = cg >> 7, d = cg & 127;
    vout[(((size_t)(b * NKV + kvh)) * HD + d) * SEQ + s0 + tx] = t[tx][c];
  }
}

// ---------------- Flash attention (causal, GQA), swapped-operand 32x32 ----------------
// 512 blocks (XCD-swizzled), each handles q-tiles {qpi, 15-qpi} sequentially
// (uniform 34 staged tiles/block -> no tail). 4 waves, 32 q-rows/wave,
// lane-local softmax, P in registers, K LDS-staged (dbuf), V^T from L2.
__global__ __launch_bounds__(256, 2) void attn_kernel(const ushort* __restrict__ Qh,
                                                      const ushort* __restrict__ Kh,
                                                      const ushort* __restrict__ Vt,
                                                      ushort* __restrict__ Out) {
  __shared__ ushort Kl[2][64 * 128];  // 2 x 16KB, XOR-swizzled rows

  const int tid = threadIdx.x;
  const int w = tid >> 6, l = tid & 63;
  const int lq = l & 31;   // this lane's q column
  const int hl = l >> 5;   // lane half

  // XCD-aware decode: XCD (n%8) owns (b,kvh) pairs {2x,2x+1}
  const int n = blockIdx.x;           // [0,512)
  const int m = ((n & 7) << 6) + (n >> 3);
  const int pp = m >> 5;              // bb*8 + kvh
  const int rm = m & 31;
  const int h2 = rm >> 3;             // head within group
  const int qpi = rm & 7;             // q-tile pair index
  const int bb = pp >> 3, kvh = pp & 7;
  const int hh = kvh * 4 + h2;
  const int bh = bb * 32 + hh;

  const ushort* Kbase = Kh + ((size_t)(bb * NKV + kvh) * SEQ) * HD;
  const ushort* Vbase = Vt + ((size_t)(bb * NKV + kvh) * HD) * SEQ;

  auto stageK = [&](int buf, int t) {
    const int kv0 = t * 64;
#pragma unroll
    for (int q = 0; q < 4; ++q) {
      int chunk = 4 * w + q;
      int row = chunk * 4 + (l >> 4);
      int cs = ((l & 15) ^ (row & 7)) * 8;
      gload16(Kbase + ((size_t)(kv0 + row)) * HD + cs, &Kl[buf][chunk * 512]);
    }
  };

  for (int qsel = 0; qsel < 2; ++qsel) {
    const int qt = qsel ? (15 - qpi) : qpi;
    const int q0 = qt * 128;
    const int wrow0 = q0 + 32 * w;
    const int qrow = wrow0 + lq;

    // Q fragments (B-operand: col=q=lane&31, k = 8*hl + j per 16-step)
    bf16x8 qf[8];
    {
      const ushort* qrp = Qh + ((size_t)bh * SEQ + qrow) * HD + 8 * hl;
#pragma unroll
      for (int s8 = 0; s8 < 8; ++s8) qf[s8] = *(const bf16x8*)(qrp + 16 * s8);
    }

    f32x16 o[4];
#pragma unroll
    for (int db = 0; db < 4; ++db)
#pragma unroll
      for (int i = 0; i < 16; ++i) o[db][i] = 0.f;
    float m_run = -1e30f, l_run = 0.f;

    const int ntw = 2 * qt + (w >> 1) + 1;  // this wave's causal tile count
    const int ntb = 2 * qt + 2;             // block tile count

    stageK(0, 0);
    __syncthreads();

    int cur = 0;
    for (int t = 0; t < ntb; ++t) {
      const int kv0 = t * 64;
      if (t + 1 < ntb) stageK(cur ^ 1, t + 1);

      if (t < ntw) {
        // S^T = K * Q : C[row=kv][col=q]
        f32x16 sacc[2];
#pragma unroll
        for (int b2 = 0; b2 < 2; ++b2)
#pragma unroll
          for (int i = 0; i < 16; ++i) sacc[b2][i] = 0.f;

        const int swz = lq & 7;
        __builtin_amdgcn_s_setprio(1);
#pragma unroll
        for (int s8 = 0; s8 < 8; ++s8) {
#pragma unroll
          for (int b2 = 0; b2 < 2; ++b2) {
            int row = 32 * b2 + lq;
            bf16x8 kf = *(const bf16x8*)((const char*)&Kl[cur][0] + row * 256 +
                                         (((2 * s8 + hl) ^ swz) << 4));
            sacc[b2] = __builtin_amdgcn_mfma_f32_32x32x16_bf16(kf, qf[s8], sacc[b2], 0, 0, 0);
          }
        }
        __builtin_amdgcn_s_setprio(0);

        if (t == ntw - 1) {  // diagonal tile: causal mask (kv > q)
#pragma unroll
          for (int b2 = 0; b2 < 2; ++b2)
#pragma unroll
            for (int r = 0; r < 16; ++r) {
              int kv = kv0 + 32 * b2 + (r & 3) + 8 * (r >> 2) + 4 * hl;
              if (kv > qrow) sacc[b2][r] = -1e30f;
            }
        }

        // lane-local softmax
        float mx = sacc[0][0];
#pragma unroll
        for (int r = 1; r < 16; ++r) mx = fmaxf(mx, sacc[0][r]);
#pragma unroll
        for (int r = 0; r < 16; ++r) mx = fmaxf(mx, sacc[1][r]);
        mx = fmaxf(mx, __shfl_xor(mx, 32));

        if (__any(mx > m_run + 8.0f)) {  // defer-max (T13)
          float mn = fmaxf(m_run, mx);
          float sc = __expf(m_run - mn);
          m_run = mn;
          l_run *= sc;
#pragma unroll
          for (int db = 0; db < 4; ++db) o[db] *= sc;
        }

        float sum = 0.f;
#pragma unroll
        for (int b2 = 0; b2 < 2; ++b2)
#pragma unroll
          for (int r = 0; r < 16; ++r) {
            float e = __expf(sacc[b2][r] - m_run);
            sacc[b2][r] = e;
            sum += e;
          }
        sum += __shfl_xor(sum, 32);
        l_run += sum;

        // pack P to bf16 pairs
        unsigned pw[2][8];
#pragma unroll
        for (int b2 = 0; b2 < 2; ++b2)
#pragma unroll
          for (int i = 0; i < 8; ++i)
            pw[b2][i] = cvt_pk_bf16(sacc[b2][2 * i], sacc[b2][2 * i + 1]);

        // O^T += V^T * P
#pragma unroll
        for (int s = 0; s < 4; ++s) {
          const int b2 = s >> 1, bs = 4 * (s & 1);
          unsigned wA = pw[b2][bs], wB = pw[b2][bs + 1], wC = pw[b2][bs + 2], wD = pw[b2][bs + 3];
          unsigned s1 = hl ? wA : wC, s2 = hl ? wB : wD;
          unsigned rx1 = (unsigned)__shfl_xor((int)s1, 32);
          unsigned rx2 = (unsigned)__shfl_xor((int)s2, 32);
          u32x4 fw = {hl ? rx1 : wA, hl ? rx2 : wB, hl ? wC : rx1, hl ? wD : rx2};
          bf16x8 pfrag = __builtin_bit_cast(bf16x8, fw);
          const ushort* vp = Vbase + (size_t)lq * SEQ + kv0 + 16 * s + 8 * hl;
          bf16x8 vf[4];
#pragma unroll
          for (int db = 0; db < 4; ++db) vf[db] = *(const bf16x8*)(vp + (size_t)(32 * db) * SEQ);
          __builtin_amdgcn_s_setprio(1);
#pragma unroll
          for (int db = 0; db < 4; ++db)
            o[db] = __builtin_amdgcn_mfma_f32_32x32x16_bf16(vf[db], pfrag, o[db], 0, 0, 0);
          __builtin_amdgcn_s_setprio(0);
        }
      }
      __syncthreads();
      cur ^= 1;
    }

    // write O^T: lane's column q = qrow; rows d = 32db + (r&3)+8*(r>>2)+4*hl
    const float inv = 1.0f / l_run;
    ushort* outp = Out + ((size_t)bb * SEQ + qrow) * (NH * HD) + hh * HD;
#pragma unroll
    for (int db = 0; db < 4; ++db)
#pragma unroll
      for (int i = 0; i < 8; ++i) {
        unsigned wrd = cvt_pk_bf16(o[db][2 * i] * inv, o[db][2 * i + 1] * inv);
        int d = 32 * db + 2 * (i & 1) + 8 * (i >> 1) + 4 * hl;
        *(unsigned*)(outp + d) = wrd;
      }
  }
}

extern "C" void kernel_launch(void* const* d_in, const int* in_sizes, int n_in,
                              void* d_out, int out_size, void* d_ws, size_t ws_size,
                              hipStream_t stream) {
  const float* hs = (const float*)d_in[0];
  // d_in[1] = attention_mask: exactly causal, applied analytically in attn_kernel
  const float* cosb = (const float*)d_in[2];
  const float* sinb = (const float*)d_in[3];
  const float* wq = (const float*)d_in[4];
  const float* wk = (const float*)d_in[5];
  const float* wv = (const float*)d_in[6];
  const float* wo = (const float*)d_in[7];

  char* ws = (char*)d_ws;
  ushort* hs_bf = (ushort*)(ws);               // 33.5MB [4096][4096]
  ushort* wq_bf = (ushort*)(ws + 33554432);    // 33.5MB
  ushort* wk_bf = (ushort*)(ws + 67108864);    // 8.4MB
  ushort* wv_bf = (ushort*)(ws + 75497472);    // 8.4MB
  ushort* wo_bf = (ushort*)(ws + 83886080);    // 33.5MB
  ushort* q_lin = (ushort*)(ws + 117440512);   // 33.5MB [4096][4096]
  ushort* k_lin = (ushort*)(ws + 150994944);   // 8.4MB  [4096][1024]
  ushort* v_lin = (ushort*)(ws + 159383552);   // 8.4MB  (ends at 160MB)
  // aliases into regions dead after the projections:
  ushort* Qh = hs_bf;                          // [B][32][S][128]
  ushort* Kh = wq_bf;                          // [B][8][S][128]
  ushort* Vt = (ushort*)(ws + 41943040);       // [B][8][128][S]
  ushort* attn_out = q_lin;                    // [4096][4096]

  f2bf_kernel<<<16384, 256, 0, stream>>>((const float4*)hs, (ushort4*)hs_bf, 4194304);
  f2bf_kernel<<<16384, 256, 0, stream>>>((const float4*)wq, (ushort4*)wq_bf, 4194304);
  f2bf_kernel<<<4096, 256, 0, stream>>>((const float4*)wk, (ushort4*)wk_bf, 1048576);
  f2bf_kernel<<<4096, 256, 0, stream>>>((const float4*)wv, (ushort4*)wv_bf, 1048576);
  f2bf_kernel<<<16384, 256, 0, stream>>>((const float4*)wo, (ushort4*)wo_bf, 4194304);

  gemm256_kernel<0><<<256, 512, 0, stream>>>(hs_bf, wq_bf, q_lin, 4096, 4096, 4096);
  gemm_bt_kernel<0><<<dim3(8, 32), 256, 0, stream>>>(hs_bf, wk_bf, k_lin, 4096, 1024, 4096);
  gemm_bt_kernel<0><<<dim3(8, 32), 256, 0, stream>>>(hs_bf, wv_bf, v_lin, 4096, 1024, 4096);

  rope_kernel<<<32768, 256, 0, stream>>>(q_lin, cosb, sinb, Qh, 5, 0.08838834764831845f);
  rope_kernel<<<8192, 256, 0, stream>>>(k_lin, cosb, sinb, Kh, 3, 1.0f);
  vtrans_kernel<<<dim3(32, 16, 2), 256, 0, stream>>>(v_lin, Vt);

  attn_kernel<<<512, 256, 0, stream>>>(Qh, Kh, Vt, attn_out);

  gemm256_kernel<1><<<256, 512, 0, stream>>>(attn_out, wo_bf, d_out, 4096, 4096, 4096);
}